// Round 3
// baseline (705.936 us; speedup 1.0000x reference)
//
#include <hip/hip_runtime.h>
#include <math.h>

#define B_ 32
#define TX_ 512
#define TY_ 2048
#define D_ 80
#define NEG (-1e9f)
#define PF 16

// ---------------------------------------------------------------------------
// prep: A1 = exp(-2*x_logs), A2 = x_m*A1, Cc = sum_d(-0.5*log(2pi) - x_logs
//       - 0.5*x_m^2*A1). Also sets *flag=1 if any x_logs != 0.
// ---------------------------------------------------------------------------
__global__ __launch_bounds__(128) void prep_kernel(
    const float* __restrict__ x_m, const float* __restrict__ x_logs,
    float* __restrict__ A1, float* __restrict__ A2, float* __restrict__ Cc,
    int* __restrict__ flag)
{
    int row = blockIdx.x;            // b*TX + x
    int t = threadIdx.x;
    __shared__ float red[128];
    float contrib = 0.f;
    bool nz = false;
    if (t < D_) {
        float xl = x_logs[(size_t)row * D_ + t];
        float xm = x_m[(size_t)row * D_ + t];
        nz = (xl != 0.f);
        float a1 = expf(-2.f * xl);
        float a2 = xm * a1;
        A1[(size_t)row * D_ + t] = a1;
        A2[(size_t)row * D_ + t] = a2;
        contrib = -0.91893853320467274178f - xl - 0.5f * xm * xm * a1;
    }
    unsigned long long m = __ballot(nz);
    if ((t & 63) == 0 && m) atomicOr(flag, 1);
    red[t] = contrib;
    __syncthreads();
    if (t < 64) {
        float v = red[t] + red[t + 64];
        #pragma unroll
        for (int off = 32; off >= 1; off >>= 1) v += __shfl_down(v, off);
        if (t == 0) Cc[row] = v;
    }
}

// ---------------------------------------------------------------------------
// lengths: lens[b] = round(sum x_mask[b]), lens[B+b] = round(sum z_mask[b])
// ---------------------------------------------------------------------------
__global__ __launch_bounds__(256) void lens_kernel(const float* __restrict__ x_mask,
    const float* __restrict__ z_mask, int* __restrict__ lens)
{
    int blk = blockIdx.x; int t = threadIdx.x;
    __shared__ float red[256];
    float s = 0.f;
    if (blk < B_) {
        for (int i = t; i < TX_; i += 256) s += x_mask[(size_t)blk * TX_ + i];
    } else {
        int b = blk - B_;
        for (int i = t; i < TY_; i += 256) s += z_mask[(size_t)b * TY_ + i];
    }
    red[t] = s; __syncthreads();
    for (int off = 128; off >= 1; off >>= 1) {
        if (t < off) red[t] += red[t + off];
        __syncthreads();
    }
    if (t == 0) lens[blk] = (int)(red[0] + 0.5f);
}

// ---------------------------------------------------------------------------
// gemm_zero: fast path when all x_logs == 0 (a1==1, a2==x_m):
// logpT[b][y-y0][x] = Cc[x] + sum_d(-0.5 z^2) + sum_d x_m[x,d]*z[d,y], masked.
// Szz computed in-block from the staged z tile (saves a full z re-read).
// 128x64 tile, 1 fma per MAC.  Early-exits if flag!=0.
// ---------------------------------------------------------------------------
__global__ __launch_bounds__(256) void gemm_zero(
    const int* __restrict__ flag,
    const float* __restrict__ x_m, const float* __restrict__ Cc,
    const float* __restrict__ z,
    const float* __restrict__ x_mask, const float* __restrict__ z_mask,
    float* __restrict__ logpT, int y0, int C)
{
    if (*flag != 0) return;
    __shared__ float xs[D_][136];    // 128 + 8 pad
    __shared__ float zs[D_][64];
    int b = blockIdx.z;
    int x0 = blockIdx.x * 128;
    int cy0 = blockIdx.y * 64;
    int yy0 = y0 + cy0;
    int tid = threadIdx.x;
    for (int i = tid; i < 128 * D_; i += 256) {
        int m = i / D_, d = i - m * D_;
        xs[d][m] = x_m[((size_t)(b * TX_ + x0 + m)) * D_ + d];
    }
    for (int i = tid; i < D_ * 64; i += 256) {
        int d = i >> 6, n = i & 63;
        zs[d][n] = z[((size_t)(b * D_ + d)) * TY_ + yy0 + n];
    }
    __syncthreads();
    int tm = tid & 15, tn = tid >> 4;
    float acc[8][4];
    float accz[4] = {0.f, 0.f, 0.f, 0.f};
    #pragma unroll
    for (int i = 0; i < 8; ++i)
        #pragma unroll
        for (int j = 0; j < 4; ++j) acc[i][j] = 0.f;
    #pragma unroll 4
    for (int k = 0; k < D_; ++k) {
        float4 a0 = *(const float4*)&xs[k][tm * 8];
        float4 a1v = *(const float4*)&xs[k][tm * 8 + 4];
        float4 zv = *(const float4*)&zs[k][tn * 4];
        float av[8] = {a0.x, a0.y, a0.z, a0.w, a1v.x, a1v.y, a1v.z, a1v.w};
        float zvv[4] = {zv.x, zv.y, zv.z, zv.w};
        #pragma unroll
        for (int j = 0; j < 4; ++j) {
            accz[j] = fmaf(zvv[j], zvv[j], accz[j]);
            #pragma unroll
            for (int i = 0; i < 8; ++i)
                acc[i][j] = fmaf(av[i], zvv[j], acc[i][j]);
        }
    }
    float4 cc0 = *(const float4*)&Cc[(size_t)b * TX_ + x0 + tm * 8];
    float4 cc1 = *(const float4*)&Cc[(size_t)b * TX_ + x0 + tm * 8 + 4];
    float4 xm0 = *(const float4*)&x_mask[(size_t)b * TX_ + x0 + tm * 8];
    float4 xm1 = *(const float4*)&x_mask[(size_t)b * TX_ + x0 + tm * 8 + 4];
    float ccv[8] = {cc0.x, cc0.y, cc0.z, cc0.w, cc1.x, cc1.y, cc1.z, cc1.w};
    float xmv[8] = {xm0.x, xm0.y, xm0.z, xm0.w, xm1.x, xm1.y, xm1.z, xm1.w};
    #pragma unroll
    for (int j = 0; j < 4; ++j) {
        int n = tn * 4 + j;
        float zmv = z_mask[(size_t)b * TY_ + yy0 + n];
        float sz = -0.5f * accz[j];
        float4 o0, o1;
        float* ov0 = (float*)&o0; float* ov1 = (float*)&o1;
        #pragma unroll
        for (int i = 0; i < 4; ++i) {
            float v0 = acc[i][j] + ccv[i] + sz;
            float v1 = acc[i + 4][j] + ccv[i + 4] + sz;
            ov0[i] = (xmv[i] * zmv > 0.f) ? v0 : NEG;
            ov1[i] = (xmv[i + 4] * zmv > 0.f) ? v1 : NEG;
        }
        float* orow = &logpT[((size_t)b * C + cy0 + n) * TX_ + x0 + tm * 8];
        *(float4*)orow = o0;
        *(float4*)(orow + 4) = o1;
    }
}

// ---------------------------------------------------------------------------
// gemm_logp (general path): logpT = Cc + sum_d A1*(-0.5 z^2) + A2*z, masked.
// Early-exits if flag==0 (zero path handled it).
// ---------------------------------------------------------------------------
__global__ __launch_bounds__(256) void gemm_logp(
    const int* __restrict__ flag,
    const float* __restrict__ A1, const float* __restrict__ A2, const float* __restrict__ Cc,
    const float* __restrict__ z, const float* __restrict__ x_mask, const float* __restrict__ z_mask,
    float* __restrict__ logpT, int y0, int C)
{
    if (*flag == 0) return;
    __shared__ float A1s[D_][72];
    __shared__ float A2s[D_][72];
    __shared__ float zs[D_][64];
    int b = blockIdx.z;
    int x0 = blockIdx.x * 64;
    int cy0 = blockIdx.y * 64;
    int yy0 = y0 + cy0;
    int tid = threadIdx.x;
    for (int i = tid; i < 64 * D_; i += 256) {
        int m = i / D_, d = i - m * D_;
        size_t ga = ((size_t)(b * TX_ + x0 + m)) * D_ + d;
        A1s[d][m] = A1[ga];
        A2s[d][m] = A2[ga];
    }
    for (int i = tid; i < D_ * 64; i += 256) {
        int d = i >> 6, n = i & 63;
        zs[d][n] = z[((size_t)(b * D_ + d)) * TY_ + yy0 + n];
    }
    __syncthreads();
    int tm = tid & 15, tn = tid >> 4;
    float acc[4][4];
    #pragma unroll
    for (int i = 0; i < 4; ++i)
        #pragma unroll
        for (int j = 0; j < 4; ++j) acc[i][j] = 0.f;
    #pragma unroll 4
    for (int k = 0; k < D_; ++k) {
        float4 a1 = *(const float4*)&A1s[k][tm * 4];
        float4 a2 = *(const float4*)&A2s[k][tm * 4];
        float4 zv = *(const float4*)&zs[k][tn * 4];
        float av1[4] = {a1.x, a1.y, a1.z, a1.w};
        float av2[4] = {a2.x, a2.y, a2.z, a2.w};
        float zvv[4] = {zv.x, zv.y, zv.z, zv.w};
        #pragma unroll
        for (int j = 0; j < 4; ++j) {
            float h = -0.5f * zvv[j];
            #pragma unroll
            for (int i = 0; i < 4; ++i) {
                float tt = fmaf(h, av1[i], av2[i]);
                acc[i][j] = fmaf(zvv[j], tt, acc[i][j]);
            }
        }
    }
    float4 cc = *(const float4*)&Cc[(size_t)b * TX_ + x0 + tm * 4];
    float4 xm = *(const float4*)&x_mask[(size_t)b * TX_ + x0 + tm * 4];
    float ccv[4] = {cc.x, cc.y, cc.z, cc.w};
    float xmv[4] = {xm.x, xm.y, xm.z, xm.w};
    #pragma unroll
    for (int j = 0; j < 4; ++j) {
        int n = tn * 4 + j;
        float zmv = z_mask[(size_t)b * TY_ + yy0 + n];
        float4 o;
        float* ov = (float*)&o;
        #pragma unroll
        for (int i = 0; i < 4; ++i) {
            float val = acc[i][j] + ccv[i];
            ov[i] = (xmv[i] * zmv > 0.f) ? val : NEG;
        }
        *(float4*)&logpT[((size_t)b * C + cy0 + n) * TX_ + x0 + tm * 4] = o;
    }
}

// ---------------------------------------------------------------------------
// Viterbi forward. One wave per batch, lane holds x = lane*8 + j.
// PF=16 register ring hides load latency; decision bytes staged in LDS and
// flushed every 16 steps as one coalesced dwordx4 store per lane (keeps slow
// partial-line byte stores OUT of the in-order vmcnt retire stream).
// ---------------------------------------------------------------------------
__device__ __forceinline__ unsigned int dp_stepN_b(int lane, const float4 la, const float4 lb,
    float (&f)[8], unsigned int laneMask)
{
    float lp8[8] = {la.x, la.y, la.z, la.w, lb.x, lb.y, lb.z, lb.w};
    float sh = __shfl_up(f[7], 1);
    float pm0 = (lane == 0) ? NEG : sh;
    unsigned int byt = 0u;
    #pragma unroll
    for (int j = 7; j >= 0; --j) {            // descending: f[j-1] still old
        float pm = (j == 0) ? pm0 : f[j - 1];
        byt = byt * 2u + ((f[j] < pm) ? 1u : 0u);
        f[j] = lp8[j] + fmaxf(pm, f[j]);
    }
    return byt & laneMask;
}

__device__ __forceinline__ unsigned int dp_stepD_b(int y, int lane, const float4 la, const float4 lb,
    float (&f)[8], unsigned int laneMask)
{
    float lp8[8] = {la.x, la.y, la.z, la.w, lb.x, lb.y, lb.z, lb.w};
    float sh = __shfl_up(f[7], 1);
    float edge = (y == 0) ? 0.f : NEG;
    float pm0 = (lane == 0) ? edge : sh;
    bool lanehit = (lane == (y >> 3));
    int jeq = y & 7;
    unsigned int byt = 0u;
    #pragma unroll
    for (int j = 7; j >= 0; --j) {
        float pm = (j == 0) ? pm0 : f[j - 1];
        bool ceq = lanehit && (jeq == j);
        byt = byt * 2u + (((f[j] < pm) || ceq) ? 1u : 0u);
        float vc = ceq ? NEG : f[j];
        f[j] = lp8[j] + fmaxf(pm, vc);
    }
    return byt & laneMask;
}

__global__ __launch_bounds__(64) void dp_forward(const float* __restrict__ logpT,
    float* __restrict__ fsave, unsigned char* __restrict__ bits8, int y0, int C)
{
    int b = blockIdx.x, lane = threadIdx.x;
    const float* lp = logpT + (size_t)b * C * TX_ + lane * 8;
    unsigned char* bbase = bits8 + ((size_t)b * TY_ + y0) * 64;
    __shared__ unsigned char sb[16 * 64];     // [step&15][lane]
    float f[8];
    if (y0 == 0) {
        #pragma unroll
        for (int j = 0; j < 8; ++j) f[j] = NEG;
    } else {
        float4 fa = *(const float4*)(fsave + (size_t)b * TX_ + lane * 8);
        float4 fb = *(const float4*)(fsave + (size_t)b * TX_ + lane * 8 + 4);
        f[0]=fa.x; f[1]=fa.y; f[2]=fa.z; f[3]=fa.w;
        f[4]=fb.x; f[5]=fb.y; f[6]=fb.z; f[7]=fb.w;
    }
    unsigned int laneMask = (lane == 0) ? 0xFEu : 0xFFu;

    float4 bufA[PF], bufB[PF];
    #pragma unroll
    for (int s = 0; s < PF; ++s) {            // C >= 128 > PF always
        bufA[s] = *(const float4*)(lp + (size_t)s * TX_);
        bufB[s] = *(const float4*)(lp + (size_t)s * TX_ + 4);
    }
    int tD = 0;
    if (y0 < TX_) { tD = TX_ - y0; if (tD > C) tD = C; }   // multiple of 16
    int t = 0;
    for (; t < tD; t += 16) {
        #pragma unroll
        for (int s = 0; s < 16; ++s) {
            unsigned int byt = dp_stepD_b(y0 + t + s, lane, bufA[s], bufB[s], f, laneMask);
            sb[s * 64 + lane] = (unsigned char)byt;
            int tn = t + s + PF; if (tn >= C) tn = C - 1;
            bufA[s] = *(const float4*)(lp + (size_t)tn * TX_);
            bufB[s] = *(const float4*)(lp + (size_t)tn * TX_ + 4);
        }
        int4 v = ((const int4*)sb)[lane];     // transpose via LDS (in-wave ordered)
        *(int4*)(bbase + (size_t)t * 64 + (size_t)lane * 16) = v;
    }
    for (; t < C; t += 16) {
        #pragma unroll
        for (int s = 0; s < 16; ++s) {
            unsigned int byt = dp_stepN_b(lane, bufA[s], bufB[s], f, laneMask);
            sb[s * 64 + lane] = (unsigned char)byt;
            int tn = t + s + PF; if (tn >= C) tn = C - 1;
            bufA[s] = *(const float4*)(lp + (size_t)tn * TX_);
            bufB[s] = *(const float4*)(lp + (size_t)tn * TX_ + 4);
        }
        int4 v = ((const int4*)sb)[lane];
        *(int4*)(bbase + (size_t)t * 64 + (size_t)lane * 16) = v;
    }
    float4 fa = make_float4(f[0], f[1], f[2], f[3]);
    float4 fb = make_float4(f[4], f[5], f[6], f[7]);
    *(float4*)(fsave + (size_t)b * TX_ + lane * 8) = fa;
    *(float4*)(fsave + (size_t)b * TX_ + lane * 8 + 4) = fb;
}

// ---------------------------------------------------------------------------
// Backtrack. One wave per batch.
// ---------------------------------------------------------------------------
__global__ __launch_bounds__(64) void backtrack_kernel(
    const unsigned char* __restrict__ bits8, const int* __restrict__ lens,
    const float* __restrict__ x_mask, int* __restrict__ idxA, float* __restrict__ logdur)
{
    int b = blockIdx.x, lane = threadIdx.x;
    __shared__ int durS[TX_];
    for (int x = lane; x < TX_; x += 64) durS[x] = 0;
    int tx_len = lens[b];
    int ty_len = lens[B_ + b];
    int idx = tx_len - 1;
    if (idx < 0) idx = 0;
    int cnt = 0;
    const unsigned long long* bu = (const unsigned long long*)(bits8 + (size_t)b * TY_ * 64);
    for (int w = 0; w < TY_ / 64; ++w) {
        int ytop = TY_ - 1 - w * 64;
        int yl = ytop - lane;
        int Whi = idx >> 6;
        unsigned long long whi = bu[(size_t)yl * 8 + Whi];
        unsigned long long wlo = (Whi > 0) ? bu[(size_t)yl * 8 + Whi - 1] : 0ull;
        int rec = -1;
        for (int s = 0; s < 64; ++s) {
            int y = ytop - s;
            bool active = (y < ty_len);
            if (lane == s) rec = active ? idx : -1;
            if (active) cnt++;
            unsigned long long wsel = ((idx >> 6) == Whi) ? __shfl(whi, s) : __shfl(wlo, s);
            int bit = (int)((wsel >> (idx & 63)) & 1ull);
            if (active && bit) {
                if (lane == 0) durS[idx] = cnt;
                cnt = 0;
                idx -= 1;
            }
        }
        idxA[(size_t)b * TY_ + yl] = rec;
    }
    if (lane == 0) durS[idx] = cnt;
    __syncthreads();
    for (int x = lane; x < TX_; x += 64) {
        float dv = (float)durS[x];
        logdur[(size_t)b * TX_ + x] = logf(1e-8f + dv) * x_mask[(size_t)b * TX_ + x];
    }
}

// ---------------------------------------------------------------------------
__global__ __launch_bounds__(256) void attn_write(const int* __restrict__ idxA,
    const float* __restrict__ x_mask, const float* __restrict__ z_mask,
    float* __restrict__ attn_o)
{
    int b = blockIdx.z; int x = blockIdx.y;
    int yq = blockIdx.x * 256 + threadIdx.x;
    int4 iv = ((const int4*)(idxA + (size_t)b * TY_))[yq];
    float xm = x_mask[(size_t)b * TX_ + x];
    float4 zm4 = ((const float4*)(z_mask + (size_t)b * TY_))[yq];
    float4 o;
    o.x = (iv.x == x) ? xm * zm4.x : 0.f;
    o.y = (iv.y == x) ? xm * zm4.y : 0.f;
    o.z = (iv.z == x) ? xm * zm4.z : 0.f;
    o.w = (iv.w == x) ? xm * zm4.w : 0.f;
    ((float4*)(attn_o + ((size_t)(b * TX_ + x)) * TY_))[yq] = o;
}

__global__ __launch_bounds__(256) void zm_write(const int* __restrict__ idxA,
    const float* __restrict__ x_m, const float* __restrict__ x_logs,
    const float* __restrict__ x_mask, const float* __restrict__ z_mask,
    float* __restrict__ z_m_o, float* __restrict__ z_logs_o)
{
    int b = blockIdx.z; int d = blockIdx.y;
    int yq = blockIdx.x * 256 + threadIdx.x;
    int4 iv = ((const int4*)(idxA + (size_t)b * TY_))[yq];
    float4 zm4 = ((const float4*)(z_mask + (size_t)b * TY_))[yq];
    float4 om, ol;
    float* omv = (float*)&om; float* olv = (float*)&ol;
    int ivv[4] = {iv.x, iv.y, iv.z, iv.w};
    float zmv[4] = {zm4.x, zm4.y, zm4.z, zm4.w};
    #pragma unroll
    for (int c = 0; c < 4; ++c) {
        float vm = 0.f, vl = 0.f;
        int ix = ivv[c];
        if (ix >= 0) {
            float wgt = x_mask[(size_t)b * TX_ + ix] * zmv[c];
            size_t ga = ((size_t)(b * TX_ + ix)) * D_ + d;
            vm = wgt * x_m[ga];
            vl = wgt * x_logs[ga];
        }
        omv[c] = vm; olv[c] = vl;
    }
    ((float4*)(z_m_o    + ((size_t)(b * D_ + d)) * TY_))[yq] = om;
    ((float4*)(z_logs_o + ((size_t)(b * D_ + d)) * TY_))[yq] = ol;
}

// ---------------------------------------------------------------------------
extern "C" void kernel_launch(void* const* d_in, const int* in_sizes, int n_in,
                              void* d_out, int out_size, void* d_ws, size_t ws_size,
                              hipStream_t stream)
{
    const float* x_m    = (const float*)d_in[0];   // [B,TX,D]
    const float* x_logs = (const float*)d_in[1];   // [B,TX,D]
    const float* z      = (const float*)d_in[2];   // [B,D,TY]
    const float* x_mask = (const float*)d_in[3];   // [B,1,TX]
    const float* z_mask = (const float*)d_in[4];   // [B,1,TY]
    float* out = (float*)d_out;
    float* z_m_o    = out;                                   // [B,D,TY]
    float* z_logs_o = out + (size_t)B_ * D_ * TY_;           // [B,D,TY]
    float* logdur_o = out + (size_t)2 * B_ * D_ * TY_;       // [B,1,TX]
    float* attn_o   = logdur_o + (size_t)B_ * TX_;           // [B,TX,TY]

    char* p = (char*)d_ws;
    float* A1 = (float*)p;            p += (size_t)B_ * TX_ * D_ * 4;
    float* A2 = (float*)p;            p += (size_t)B_ * TX_ * D_ * 4;
    float* Cc = (float*)p;            p += (size_t)B_ * TX_ * 4;
    float* fs = (float*)p;            p += (size_t)B_ * TX_ * 4;
    unsigned char* bits8 = (unsigned char*)p; p += (size_t)B_ * TY_ * 64;
    int* idxA = (int*)p;              p += (size_t)B_ * TY_ * 4;
    int* lens = (int*)p;              p += 256;
    int* flag = (int*)p;              p += 256;
    float* logpC = (float*)p;
    size_t fixed = (size_t)(p - (char*)d_ws);
    size_t avail = (ws_size > fixed) ? (ws_size - fixed) : 0;
    int C = 64;                                    // Ty chunk for staged logp
    const int cands[5] = {2048, 1024, 512, 256, 128};
    for (int i = 0; i < 5; ++i) {
        if ((size_t)B_ * cands[i] * TX_ * 4 <= avail) { C = cands[i]; break; }
    }

    hipMemsetAsync(flag, 0, sizeof(int), stream);
    prep_kernel<<<B_ * TX_, 128, 0, stream>>>(x_m, x_logs, A1, A2, Cc, flag);
    lens_kernel<<<2 * B_, 256, 0, stream>>>(x_mask, z_mask, lens);
    int nc = TY_ / C;
    for (int c = 0; c < nc; ++c) {
        gemm_zero<<<dim3(TX_ / 128, C / 64, B_), 256, 0, stream>>>(
            flag, x_m, Cc, z, x_mask, z_mask, logpC, c * C, C);
        gemm_logp<<<dim3(TX_ / 64, C / 64, B_), 256, 0, stream>>>(
            flag, A1, A2, Cc, z, x_mask, z_mask, logpC, c * C, C);
        dp_forward<<<B_, 64, 0, stream>>>(logpC, fs, bits8, c * C, C);
    }
    backtrack_kernel<<<B_, 64, 0, stream>>>(bits8, lens, x_mask, idxA, logdur_o);
    attn_write<<<dim3(TY_ / 4 / 256, TX_, B_), 256, 0, stream>>>(idxA, x_mask, z_mask, attn_o);
    zm_write<<<dim3(TY_ / 4 / 256, D_, B_), 256, 0, stream>>>(
        idxA, x_m, x_logs, x_mask, z_mask, z_m_o, z_logs_o);
}

// Round 6
// 673.800 us; speedup vs baseline: 1.0477x; 1.0477x over previous
//
#include <hip/hip_runtime.h>
#include <math.h>

#define B_ 32
#define TX_ 512
#define TY_ 2048
#define D_ 80
#define NEG (-1e9f)
#define PF 8

typedef float f32x4 __attribute__((ext_vector_type(4)));

// ---------------------------------------------------------------------------
// prep: Cc = sum_d(-0.5*log(2pi) - x_logs - 0.5*x_m^2*exp(-2*x_logs)).
// Sets *flag=1 if any x_logs != 0 (selects general vs fast gemm path).
// ---------------------------------------------------------------------------
__global__ __launch_bounds__(128) void prep_kernel(
    const float* __restrict__ x_m, const float* __restrict__ x_logs,
    float* __restrict__ Cc, int* __restrict__ flag)
{
    int row = blockIdx.x;            // b*TX + x
    int t = threadIdx.x;
    __shared__ float red[128];
    float contrib = 0.f;
    bool nz = false;
    if (t < D_) {
        float xl = x_logs[(size_t)row * D_ + t];
        float xm = x_m[(size_t)row * D_ + t];
        nz = (xl != 0.f);
        float a1 = expf(-2.f * xl);
        contrib = -0.91893853320467274178f - xl - 0.5f * xm * xm * a1;
    }
    unsigned long long m = __ballot(nz);
    if ((t & 63) == 0 && m) atomicOr(flag, 1);
    red[t] = contrib;
    __syncthreads();
    if (t < 64) {
        float v = red[t] + red[t + 64];
        #pragma unroll
        for (int off = 32; off >= 1; off >>= 1) v += __shfl_down(v, off);
        if (t == 0) Cc[row] = v;
    }
}

// ---------------------------------------------------------------------------
// lengths
// ---------------------------------------------------------------------------
__global__ __launch_bounds__(256) void lens_kernel(const float* __restrict__ x_mask,
    const float* __restrict__ z_mask, int* __restrict__ lens)
{
    int blk = blockIdx.x; int t = threadIdx.x;
    __shared__ float red[256];
    float s = 0.f;
    if (blk < B_) {
        for (int i = t; i < TX_; i += 256) s += x_mask[(size_t)blk * TX_ + i];
    } else {
        int b = blk - B_;
        for (int i = t; i < TY_; i += 256) s += z_mask[(size_t)b * TY_ + i];
    }
    red[t] = s; __syncthreads();
    for (int off = 128; off >= 1; off >>= 1) {
        if (t < off) red[t] += red[t + off];
        __syncthreads();
    }
    if (t == 0) lens[blk] = (int)(red[0] + 0.5f);
}

// ---------------------------------------------------------------------------
// gemm_zero (fast path, all x_logs==0): logpT = Cc[x] + Szz[y] + sum_d x_m*z.
// Szz computed IN-BLOCK from the staged z tile, same k-order and same
// final expression order as the R2-passing kernel -> bitwise-identical logp.
// 128x128 tile, K in two 40-halves (42KB LDS -> 3 blocks/CU), 4+4 split
// microtile so LDS reads are 2-way (free) bank aliasing.
// ---------------------------------------------------------------------------
__global__ __launch_bounds__(256) void gemm_zero(
    const int* __restrict__ flag,
    const float* __restrict__ x_m, const float* __restrict__ Cc,
    const float* __restrict__ z,
    const float* __restrict__ x_mask, const float* __restrict__ z_mask,
    float* __restrict__ logpT, int y0, int C)
{
    if (*flag != 0) return;
    __shared__ float xs[40][132];
    __shared__ float zs[40][132];
    int b = blockIdx.z;
    int x0 = blockIdx.x * 128;
    int cy0 = blockIdx.y * 128;
    int yy0 = y0 + cy0;
    int tid = threadIdx.x;
    int tm = tid & 15, tn = tid >> 4;
    float acc[8][8];
    float accz[8];
    #pragma unroll
    for (int i = 0; i < 8; ++i) {
        accz[i] = 0.f;
        #pragma unroll
        for (int j = 0; j < 8; ++j) acc[i][j] = 0.f;
    }

    for (int h = 0; h < 2; ++h) {
        if (h) __syncthreads();
        for (int i = tid; i < 128 * 40; i += 256) {
            int m = i / 40, d = i - m * 40;
            xs[d][m] = x_m[((size_t)(b * TX_ + x0 + m)) * D_ + h * 40 + d];
        }
        for (int i = tid; i < 40 * 128; i += 256) {
            int d = i >> 7, n = i & 127;
            zs[d][n] = z[((size_t)(b * D_ + h * 40 + d)) * TY_ + yy0 + n];
        }
        __syncthreads();
        #pragma unroll 4
        for (int k = 0; k < 40; ++k) {
            f32x4 a0 = *(const f32x4*)&xs[k][tm * 4];
            f32x4 a1 = *(const f32x4*)&xs[k][64 + tm * 4];
            f32x4 z0 = *(const f32x4*)&zs[k][tn * 4];
            f32x4 z1 = *(const f32x4*)&zs[k][64 + tn * 4];
            float av[8], zv[8];
            #pragma unroll
            for (int i = 0; i < 4; ++i) { av[i] = a0[i]; av[i+4] = a1[i]; zv[i] = z0[i]; zv[i+4] = z1[i]; }
            #pragma unroll
            for (int j = 0; j < 8; ++j) {
                accz[j] = fmaf(zv[j], zv[j], accz[j]);
                #pragma unroll
                for (int i = 0; i < 8; ++i)
                    acc[i][j] = fmaf(av[i], zv[j], acc[i][j]);
            }
        }
    }
    f32x4 ccA = *(const f32x4*)&Cc[(size_t)b * TX_ + x0 + tm * 4];
    f32x4 ccB = *(const f32x4*)&Cc[(size_t)b * TX_ + x0 + 64 + tm * 4];
    f32x4 xmA = *(const f32x4*)&x_mask[(size_t)b * TX_ + x0 + tm * 4];
    f32x4 xmB = *(const f32x4*)&x_mask[(size_t)b * TX_ + x0 + 64 + tm * 4];
    #pragma unroll
    for (int jj = 0; jj < 8; ++jj) {
        int n = (jj < 4) ? (tn * 4 + jj) : (64 + tn * 4 + (jj - 4));
        float zmv = z_mask[(size_t)b * TY_ + yy0 + n];
        float sz = -0.5f * accz[jj];
        f32x4 oA, oB;
        #pragma unroll
        for (int i = 0; i < 4; ++i) {
            float vA = acc[i][jj] + ccA[i] + sz;
            float vB = acc[i + 4][jj] + ccB[i] + sz;
            oA[i] = (xmA[i] * zmv > 0.f) ? vA : NEG;
            oB[i] = (xmB[i] * zmv > 0.f) ? vB : NEG;
        }
        float* orow = &logpT[((size_t)b * C + cy0 + n) * TX_ + x0];
        *(f32x4*)(orow + tm * 4) = oA;
        *(f32x4*)(orow + 64 + tm * 4) = oB;
    }
}

// ---------------------------------------------------------------------------
// gemm_logp (general path): logpT = Cc + sum_d a1*(-0.5 z^2) + a2*z, masked.
// a1,a2 computed on the fly during staging. Early-exits if flag==0.
// ---------------------------------------------------------------------------
__global__ __launch_bounds__(256) void gemm_logp(
    const int* __restrict__ flag,
    const float* __restrict__ x_m, const float* __restrict__ x_logs,
    const float* __restrict__ Cc,
    const float* __restrict__ z, const float* __restrict__ x_mask, const float* __restrict__ z_mask,
    float* __restrict__ logpT, int y0, int C)
{
    if (*flag == 0) return;
    __shared__ float A1s[D_][72];
    __shared__ float A2s[D_][72];
    __shared__ float zs[D_][64];
    int b = blockIdx.z;
    int x0 = blockIdx.x * 64;
    int cy0 = blockIdx.y * 64;
    int yy0 = y0 + cy0;
    int tid = threadIdx.x;
    for (int i = tid; i < 64 * D_; i += 256) {
        int m = i / D_, d = i - m * D_;
        size_t ga = ((size_t)(b * TX_ + x0 + m)) * D_ + d;
        float xl = x_logs[ga], xm = x_m[ga];
        float a1 = expf(-2.f * xl);
        A1s[d][m] = a1;
        A2s[d][m] = xm * a1;
    }
    for (int i = tid; i < D_ * 64; i += 256) {
        int d = i >> 6, n = i & 63;
        zs[d][n] = z[((size_t)(b * D_ + d)) * TY_ + yy0 + n];
    }
    __syncthreads();
    int tm = tid & 15, tn = tid >> 4;
    float acc[4][4];
    #pragma unroll
    for (int i = 0; i < 4; ++i)
        #pragma unroll
        for (int j = 0; j < 4; ++j) acc[i][j] = 0.f;
    #pragma unroll 4
    for (int k = 0; k < D_; ++k) {
        f32x4 a1 = *(const f32x4*)&A1s[k][tm * 4];
        f32x4 a2 = *(const f32x4*)&A2s[k][tm * 4];
        f32x4 zv = *(const f32x4*)&zs[k][tn * 4];
        #pragma unroll
        for (int j = 0; j < 4; ++j) {
            float h = -0.5f * zv[j];
            #pragma unroll
            for (int i = 0; i < 4; ++i) {
                float tt = fmaf(h, a1[i], a2[i]);
                acc[i][j] = fmaf(zv[j], tt, acc[i][j]);
            }
        }
    }
    f32x4 cc = *(const f32x4*)&Cc[(size_t)b * TX_ + x0 + tm * 4];
    f32x4 xm = *(const f32x4*)&x_mask[(size_t)b * TX_ + x0 + tm * 4];
    #pragma unroll
    for (int j = 0; j < 4; ++j) {
        int n = tn * 4 + j;
        float zmv = z_mask[(size_t)b * TY_ + yy0 + n];
        f32x4 o;
        #pragma unroll
        for (int i = 0; i < 4; ++i) {
            float val = acc[i][j] + cc[i];
            o[i] = (xm[i] * zmv > 0.f) ? val : NEG;
        }
        *(f32x4*)&logpT[((size_t)b * C + cy0 + n) * TX_ + x0 + tm * 4] = o;
    }
}

// ---------------------------------------------------------------------------
// Viterbi forward — EXACT Round-2-passing version (PF=8 plain-C ring, byte
// stores). 254us, VGPR 60, known-correct. (Register-pinned asm rings are
// unsound at HIP level: regalloc copies/spills can read VMEM dests before
// s_waitcnt — R5 post-mortem. Next attack will stage via global_load_lds.)
// ---------------------------------------------------------------------------
__device__ __forceinline__ void dp_stepN(int lane, const float4 la, const float4 lb,
    float (&f)[8], unsigned int laneMask, unsigned char* bpp)
{
    float lp8[8] = {la.x, la.y, la.z, la.w, lb.x, lb.y, lb.z, lb.w};
    float sh = __shfl_up(f[7], 1);
    float pm0 = (lane == 0) ? NEG : sh;
    unsigned int byt = 0u;
    #pragma unroll
    for (int j = 7; j >= 0; --j) {            // descending: f[j-1] still old
        float pm = (j == 0) ? pm0 : f[j - 1];
        byt = byt * 2u + ((f[j] < pm) ? 1u : 0u);
        f[j] = lp8[j] + fmaxf(pm, f[j]);
    }
    *bpp = (unsigned char)(byt & laneMask);
}

__device__ __forceinline__ void dp_stepD(int y, int lane, const float4 la, const float4 lb,
    float (&f)[8], unsigned int laneMask, unsigned char* bpp)
{
    float lp8[8] = {la.x, la.y, la.z, la.w, lb.x, lb.y, lb.z, lb.w};
    float sh = __shfl_up(f[7], 1);
    float edge = (y == 0) ? 0.f : NEG;
    float pm0 = (lane == 0) ? edge : sh;
    bool lanehit = (lane == (y >> 3));
    int jeq = y & 7;
    unsigned int byt = 0u;
    #pragma unroll
    for (int j = 7; j >= 0; --j) {
        float pm = (j == 0) ? pm0 : f[j - 1];
        bool ceq = lanehit && (jeq == j);
        byt = byt * 2u + (((f[j] < pm) || ceq) ? 1u : 0u);
        float vc = ceq ? NEG : f[j];
        f[j] = lp8[j] + fmaxf(pm, vc);
    }
    *bpp = (unsigned char)(byt & laneMask);
}

__global__ __launch_bounds__(64) void dp_forward(const float* __restrict__ logpT,
    float* __restrict__ fsave, unsigned char* __restrict__ bits8, int y0, int C)
{
    int b = blockIdx.x, lane = threadIdx.x;
    const float* lp = logpT + (size_t)b * C * TX_ + lane * 8;
    unsigned char* bp = bits8 + ((size_t)b * TY_ + y0) * 64 + lane;
    float f[8];
    if (y0 == 0) {
        #pragma unroll
        for (int j = 0; j < 8; ++j) f[j] = NEG;
    } else {
        float4 fa = *(const float4*)(fsave + (size_t)b * TX_ + lane * 8);
        float4 fb = *(const float4*)(fsave + (size_t)b * TX_ + lane * 8 + 4);
        f[0]=fa.x; f[1]=fa.y; f[2]=fa.z; f[3]=fa.w;
        f[4]=fb.x; f[5]=fb.y; f[6]=fb.z; f[7]=fb.w;
    }
    unsigned int laneMask = (lane == 0) ? 0xFEu : 0xFFu;

    float4 bufA[PF], bufB[PF];
    #pragma unroll
    for (int s = 0; s < PF; ++s) {            // C >= 128 > PF always
        bufA[s] = *(const float4*)(lp + (size_t)s * TX_);
        bufB[s] = *(const float4*)(lp + (size_t)s * TX_ + 4);
    }
    int tD = 0;
    if (y0 < TX_) { tD = TX_ - y0; if (tD > C) tD = C; }   // multiple of PF
    int t = 0;
    for (; t < tD; t += PF) {
        #pragma unroll
        for (int s = 0; s < PF; ++s) {
            dp_stepD(y0 + t + s, lane, bufA[s], bufB[s], f, laneMask, bp + (size_t)(t + s) * 64);
            int tn = t + s + PF; if (tn >= C) tn = C - 1;
            bufA[s] = *(const float4*)(lp + (size_t)tn * TX_);
            bufB[s] = *(const float4*)(lp + (size_t)tn * TX_ + 4);
        }
    }
    for (; t < C; t += PF) {
        #pragma unroll
        for (int s = 0; s < PF; ++s) {
            dp_stepN(lane, bufA[s], bufB[s], f, laneMask, bp + (size_t)(t + s) * 64);
            int tn = t + s + PF; if (tn >= C) tn = C - 1;
            bufA[s] = *(const float4*)(lp + (size_t)tn * TX_);
            bufB[s] = *(const float4*)(lp + (size_t)tn * TX_ + 4);
        }
    }
    float4 fa = make_float4(f[0], f[1], f[2], f[3]);
    float4 fb = make_float4(f[4], f[5], f[6], f[7]);
    *(float4*)(fsave + (size_t)b * TX_ + lane * 8) = fa;
    *(float4*)(fsave + (size_t)b * TX_ + lane * 8 + 4) = fb;
}

// ---------------------------------------------------------------------------
// Backtrack. One wave per batch.
// ---------------------------------------------------------------------------
__global__ __launch_bounds__(64) void backtrack_kernel(
    const unsigned char* __restrict__ bits8, const int* __restrict__ lens,
    const float* __restrict__ x_mask, int* __restrict__ idxA, float* __restrict__ logdur)
{
    int b = blockIdx.x, lane = threadIdx.x;
    __shared__ int durS[TX_];
    for (int x = lane; x < TX_; x += 64) durS[x] = 0;
    int tx_len = lens[b];
    int ty_len = lens[B_ + b];
    int idx = tx_len - 1;
    if (idx < 0) idx = 0;
    int cnt = 0;
    const unsigned long long* bu = (const unsigned long long*)(bits8 + (size_t)b * TY_ * 64);
    for (int w = 0; w < TY_ / 64; ++w) {
        int ytop = TY_ - 1 - w * 64;
        int yl = ytop - lane;
        int Whi = idx >> 6;
        unsigned long long whi = bu[(size_t)yl * 8 + Whi];
        unsigned long long wlo = (Whi > 0) ? bu[(size_t)yl * 8 + Whi - 1] : 0ull;
        int rec = -1;
        for (int s = 0; s < 64; ++s) {
            int y = ytop - s;
            bool active = (y < ty_len);
            if (lane == s) rec = active ? idx : -1;
            if (active) cnt++;
            unsigned long long wsel = ((idx >> 6) == Whi) ? __shfl(whi, s) : __shfl(wlo, s);
            int bit = (int)((wsel >> (idx & 63)) & 1ull);
            if (active && bit) {
                if (lane == 0) durS[idx] = cnt;
                cnt = 0;
                idx -= 1;
            }
        }
        idxA[(size_t)b * TY_ + yl] = rec;
    }
    if (lane == 0) durS[idx] = cnt;
    __syncthreads();
    for (int x = lane; x < TX_; x += 64) {
        float dv = (float)durS[x];
        logdur[(size_t)b * TX_ + x] = logf(1e-8f + dv) * x_mask[(size_t)b * TX_ + x];
    }
}

// ---------------------------------------------------------------------------
__global__ __launch_bounds__(256) void attn_write(const int* __restrict__ idxA,
    const float* __restrict__ x_mask, const float* __restrict__ z_mask,
    float* __restrict__ attn_o)
{
    int b = blockIdx.z; int x = blockIdx.y;
    int yq = blockIdx.x * 256 + threadIdx.x;
    int4 iv = ((const int4*)(idxA + (size_t)b * TY_))[yq];
    float xm = x_mask[(size_t)b * TX_ + x];
    float4 zm4 = ((const float4*)(z_mask + (size_t)b * TY_))[yq];
    float4 o;
    o.x = (iv.x == x) ? xm * zm4.x : 0.f;
    o.y = (iv.y == x) ? xm * zm4.y : 0.f;
    o.z = (iv.z == x) ? xm * zm4.z : 0.f;
    o.w = (iv.w == x) ? xm * zm4.w : 0.f;
    ((float4*)(attn_o + ((size_t)(b * TX_ + x)) * TY_))[yq] = o;
}

__global__ __launch_bounds__(256) void zm_write(const int* __restrict__ idxA,
    const float* __restrict__ x_m, const float* __restrict__ x_logs,
    const float* __restrict__ x_mask, const float* __restrict__ z_mask,
    float* __restrict__ z_m_o, float* __restrict__ z_logs_o)
{
    int b = blockIdx.z; int d = blockIdx.y;
    int yq = blockIdx.x * 256 + threadIdx.x;
    int4 iv = ((const int4*)(idxA + (size_t)b * TY_))[yq];
    float4 zm4 = ((const float4*)(z_mask + (size_t)b * TY_))[yq];
    float4 om, ol;
    float* omv = (float*)&om; float* olv = (float*)&ol;
    int ivv[4] = {iv.x, iv.y, iv.z, iv.w};
    float zmv[4] = {zm4.x, zm4.y, zm4.z, zm4.w};
    #pragma unroll
    for (int c = 0; c < 4; ++c) {
        float vm = 0.f, vl = 0.f;
        int ix = ivv[c];
        if (ix >= 0) {
            float wgt = x_mask[(size_t)b * TX_ + ix] * zmv[c];
            size_t ga = ((size_t)(b * TX_ + ix)) * D_ + d;
            vm = wgt * x_m[ga];
            vl = wgt * x_logs[ga];
        }
        omv[c] = vm; olv[c] = vl;
    }
    ((float4*)(z_m_o    + ((size_t)(b * D_ + d)) * TY_))[yq] = om;
    ((float4*)(z_logs_o + ((size_t)(b * D_ + d)) * TY_))[yq] = ol;
}

// ---------------------------------------------------------------------------
extern "C" void kernel_launch(void* const* d_in, const int* in_sizes, int n_in,
                              void* d_out, int out_size, void* d_ws, size_t ws_size,
                              hipStream_t stream)
{
    const float* x_m    = (const float*)d_in[0];   // [B,TX,D]
    const float* x_logs = (const float*)d_in[1];   // [B,TX,D]
    const float* z      = (const float*)d_in[2];   // [B,D,TY]
    const float* x_mask = (const float*)d_in[3];   // [B,1,TX]
    const float* z_mask = (const float*)d_in[4];   // [B,1,TY]
    float* out = (float*)d_out;
    float* z_m_o    = out;                                   // [B,D,TY]
    float* z_logs_o = out + (size_t)B_ * D_ * TY_;           // [B,D,TY]
    float* logdur_o = out + (size_t)2 * B_ * D_ * TY_;       // [B,1,TX]
    float* attn_o   = logdur_o + (size_t)B_ * TX_;           // [B,TX,TY]

    char* p = (char*)d_ws;
    float* Cc = (float*)p;            p += (size_t)B_ * TX_ * 4;
    float* fs = (float*)p;            p += (size_t)B_ * TX_ * 4;
    unsigned char* bits8 = (unsigned char*)p; p += (size_t)B_ * TY_ * 64;
    int* idxA = (int*)p;              p += (size_t)B_ * TY_ * 4;
    int* lens = (int*)p;              p += 256;
    int* flag = (int*)p;              p += 256;
    float* logpC = (float*)p;
    size_t fixed = (size_t)(p - (char*)d_ws);
    size_t avail = (ws_size > fixed) ? (ws_size - fixed) : 0;
    int C = 128;                                   // Ty chunk for staged logp
    const int cands[5] = {2048, 1024, 512, 256, 128};
    for (int i = 0; i < 5; ++i) {
        if ((size_t)B_ * cands[i] * TX_ * 4 <= avail) { C = cands[i]; break; }
    }

    hipMemsetAsync(flag, 0, sizeof(int), stream);
    prep_kernel<<<B_ * TX_, 128, 0, stream>>>(x_m, x_logs, Cc, flag);
    lens_kernel<<<2 * B_, 256, 0, stream>>>(x_mask, z_mask, lens);
    int nc = TY_ / C;
    for (int c = 0; c < nc; ++c) {
        gemm_zero<<<dim3(TX_ / 128, C / 128, B_), 256, 0, stream>>>(
            flag, x_m, Cc, z, x_mask, z_mask, logpC, c * C, C);
        gemm_logp<<<dim3(TX_ / 64, C / 64, B_), 256, 0, stream>>>(
            flag, x_m, x_logs, Cc, z, x_mask, z_mask, logpC, c * C, C);
        dp_forward<<<B_, 64, 0, stream>>>(logpC, fs, bits8, c * C, C);
    }
    backtrack_kernel<<<B_, 64, 0, stream>>>(bits8, lens, x_mask, idxA, logdur_o);
    attn_write<<<dim3(TY_ / 4 / 256, TX_, B_), 256, 0, stream>>>(idxA, x_mask, z_mask, attn_o);
    zm_write<<<dim3(TY_ / 4 / 256, D_, B_), 256, 0, stream>>>(
        idxA, x_m, x_logs, x_mask, z_mask, z_m_o, z_logs_o);
}

// Round 7
// 651.960 us; speedup vs baseline: 1.0828x; 1.0335x over previous
//
#include <hip/hip_runtime.h>
#include <math.h>

#define B_ 32
#define TX_ 512
#define TY_ 2048
#define D_ 80
#define NEG (-1e9f)
#define PF 16

typedef float f32x4 __attribute__((ext_vector_type(4)));

// ---------------------------------------------------------------------------
// prep: Cc = sum_d(-0.5*log(2pi) - x_logs - 0.5*x_m^2*exp(-2*x_logs)).
// Sets *flag=1 if any x_logs != 0 (selects general vs fast gemm path).
// ---------------------------------------------------------------------------
__global__ __launch_bounds__(128) void prep_kernel(
    const float* __restrict__ x_m, const float* __restrict__ x_logs,
    float* __restrict__ Cc, int* __restrict__ flag)
{
    int row = blockIdx.x;            // b*TX + x
    int t = threadIdx.x;
    __shared__ float red[128];
    float contrib = 0.f;
    bool nz = false;
    if (t < D_) {
        float xl = x_logs[(size_t)row * D_ + t];
        float xm = x_m[(size_t)row * D_ + t];
        nz = (xl != 0.f);
        float a1 = expf(-2.f * xl);
        contrib = -0.91893853320467274178f - xl - 0.5f * xm * xm * a1;
    }
    unsigned long long m = __ballot(nz);
    if ((t & 63) == 0 && m) atomicOr(flag, 1);
    red[t] = contrib;
    __syncthreads();
    if (t < 64) {
        float v = red[t] + red[t + 64];
        #pragma unroll
        for (int off = 32; off >= 1; off >>= 1) v += __shfl_down(v, off);
        if (t == 0) Cc[row] = v;
    }
}

// ---------------------------------------------------------------------------
// lengths
// ---------------------------------------------------------------------------
__global__ __launch_bounds__(256) void lens_kernel(const float* __restrict__ x_mask,
    const float* __restrict__ z_mask, int* __restrict__ lens)
{
    int blk = blockIdx.x; int t = threadIdx.x;
    __shared__ float red[256];
    float s = 0.f;
    if (blk < B_) {
        for (int i = t; i < TX_; i += 256) s += x_mask[(size_t)blk * TX_ + i];
    } else {
        int b = blk - B_;
        for (int i = t; i < TY_; i += 256) s += z_mask[(size_t)b * TY_ + i];
    }
    red[t] = s; __syncthreads();
    for (int off = 128; off >= 1; off >>= 1) {
        if (t < off) red[t] += red[t + off];
        __syncthreads();
    }
    if (t == 0) lens[blk] = (int)(red[0] + 0.5f);
}

// ---------------------------------------------------------------------------
// gemm_zero (fast path, all x_logs==0): logpT = Cc[x] + Szz[y] + sum_d x_m*z.
// Szz computed IN-BLOCK from the staged z tile, same k-order and same
// final expression order as the R2-passing kernel -> bitwise-identical logp.
// 128x128 tile, K in two 40-halves (42KB LDS -> 3 blocks/CU), 4+4 split
// microtile so LDS reads are 2-way (free) bank aliasing.
// ---------------------------------------------------------------------------
__global__ __launch_bounds__(256) void gemm_zero(
    const int* __restrict__ flag,
    const float* __restrict__ x_m, const float* __restrict__ Cc,
    const float* __restrict__ z,
    const float* __restrict__ x_mask, const float* __restrict__ z_mask,
    float* __restrict__ logpT, int y0, int C)
{
    if (*flag != 0) return;
    __shared__ float xs[40][132];
    __shared__ float zs[40][132];
    int b = blockIdx.z;
    int x0 = blockIdx.x * 128;
    int cy0 = blockIdx.y * 128;
    int yy0 = y0 + cy0;
    int tid = threadIdx.x;
    int tm = tid & 15, tn = tid >> 4;
    float acc[8][8];
    float accz[8];
    #pragma unroll
    for (int i = 0; i < 8; ++i) {
        accz[i] = 0.f;
        #pragma unroll
        for (int j = 0; j < 8; ++j) acc[i][j] = 0.f;
    }

    for (int h = 0; h < 2; ++h) {
        if (h) __syncthreads();
        for (int i = tid; i < 128 * 40; i += 256) {
            int m = i / 40, d = i - m * 40;
            xs[d][m] = x_m[((size_t)(b * TX_ + x0 + m)) * D_ + h * 40 + d];
        }
        for (int i = tid; i < 40 * 128; i += 256) {
            int d = i >> 7, n = i & 127;
            zs[d][n] = z[((size_t)(b * D_ + h * 40 + d)) * TY_ + yy0 + n];
        }
        __syncthreads();
        #pragma unroll 4
        for (int k = 0; k < 40; ++k) {
            f32x4 a0 = *(const f32x4*)&xs[k][tm * 4];
            f32x4 a1 = *(const f32x4*)&xs[k][64 + tm * 4];
            f32x4 z0 = *(const f32x4*)&zs[k][tn * 4];
            f32x4 z1 = *(const f32x4*)&zs[k][64 + tn * 4];
            float av[8], zv[8];
            #pragma unroll
            for (int i = 0; i < 4; ++i) { av[i] = a0[i]; av[i+4] = a1[i]; zv[i] = z0[i]; zv[i+4] = z1[i]; }
            #pragma unroll
            for (int j = 0; j < 8; ++j) {
                accz[j] = fmaf(zv[j], zv[j], accz[j]);
                #pragma unroll
                for (int i = 0; i < 8; ++i)
                    acc[i][j] = fmaf(av[i], zv[j], acc[i][j]);
            }
        }
    }
    f32x4 ccA = *(const f32x4*)&Cc[(size_t)b * TX_ + x0 + tm * 4];
    f32x4 ccB = *(const f32x4*)&Cc[(size_t)b * TX_ + x0 + 64 + tm * 4];
    f32x4 xmA = *(const f32x4*)&x_mask[(size_t)b * TX_ + x0 + tm * 4];
    f32x4 xmB = *(const f32x4*)&x_mask[(size_t)b * TX_ + x0 + 64 + tm * 4];
    #pragma unroll
    for (int jj = 0; jj < 8; ++jj) {
        int n = (jj < 4) ? (tn * 4 + jj) : (64 + tn * 4 + (jj - 4));
        float zmv = z_mask[(size_t)b * TY_ + yy0 + n];
        float sz = -0.5f * accz[jj];
        f32x4 oA, oB;
        #pragma unroll
        for (int i = 0; i < 4; ++i) {
            float vA = acc[i][jj] + ccA[i] + sz;
            float vB = acc[i + 4][jj] + ccB[i] + sz;
            oA[i] = (xmA[i] * zmv > 0.f) ? vA : NEG;
            oB[i] = (xmB[i] * zmv > 0.f) ? vB : NEG;
        }
        float* orow = &logpT[((size_t)b * C + cy0 + n) * TX_ + x0];
        *(f32x4*)(orow + tm * 4) = oA;
        *(f32x4*)(orow + 64 + tm * 4) = oB;
    }
}

// ---------------------------------------------------------------------------
// gemm_logp (general path): logpT = Cc + sum_d a1*(-0.5 z^2) + a2*z, masked.
// a1,a2 computed on the fly during staging. Early-exits if flag==0.
// ---------------------------------------------------------------------------
__global__ __launch_bounds__(256) void gemm_logp(
    const int* __restrict__ flag,
    const float* __restrict__ x_m, const float* __restrict__ x_logs,
    const float* __restrict__ Cc,
    const float* __restrict__ z, const float* __restrict__ x_mask, const float* __restrict__ z_mask,
    float* __restrict__ logpT, int y0, int C)
{
    if (*flag == 0) return;
    __shared__ float A1s[D_][72];
    __shared__ float A2s[D_][72];
    __shared__ float zs[D_][64];
    int b = blockIdx.z;
    int x0 = blockIdx.x * 64;
    int cy0 = blockIdx.y * 64;
    int yy0 = y0 + cy0;
    int tid = threadIdx.x;
    for (int i = tid; i < 64 * D_; i += 256) {
        int m = i / D_, d = i - m * D_;
        size_t ga = ((size_t)(b * TX_ + x0 + m)) * D_ + d;
        float xl = x_logs[ga], xm = x_m[ga];
        float a1 = expf(-2.f * xl);
        A1s[d][m] = a1;
        A2s[d][m] = xm * a1;
    }
    for (int i = tid; i < D_ * 64; i += 256) {
        int d = i >> 6, n = i & 63;
        zs[d][n] = z[((size_t)(b * D_ + d)) * TY_ + yy0 + n];
    }
    __syncthreads();
    int tm = tid & 15, tn = tid >> 4;
    float acc[4][4];
    #pragma unroll
    for (int i = 0; i < 4; ++i)
        #pragma unroll
        for (int j = 0; j < 4; ++j) acc[i][j] = 0.f;
    #pragma unroll 4
    for (int k = 0; k < D_; ++k) {
        f32x4 a1 = *(const f32x4*)&A1s[k][tm * 4];
        f32x4 a2 = *(const f32x4*)&A2s[k][tm * 4];
        f32x4 zv = *(const f32x4*)&zs[k][tn * 4];
        #pragma unroll
        for (int j = 0; j < 4; ++j) {
            float h = -0.5f * zv[j];
            #pragma unroll
            for (int i = 0; i < 4; ++i) {
                float tt = fmaf(h, a1[i], a2[i]);
                acc[i][j] = fmaf(zv[j], tt, acc[i][j]);
            }
        }
    }
    f32x4 cc = *(const f32x4*)&Cc[(size_t)b * TX_ + x0 + tm * 4];
    f32x4 xm = *(const f32x4*)&x_mask[(size_t)b * TX_ + x0 + tm * 4];
    #pragma unroll
    for (int j = 0; j < 4; ++j) {
        int n = tn * 4 + j;
        float zmv = z_mask[(size_t)b * TY_ + yy0 + n];
        f32x4 o;
        #pragma unroll
        for (int i = 0; i < 4; ++i) {
            float val = acc[i][j] + cc[i];
            o[i] = (xm[i] * zmv > 0.f) ? val : NEG;
        }
        *(f32x4*)&logpT[((size_t)b * C + cy0 + n) * TX_ + x0 + tm * 4] = o;
    }
}

// ---------------------------------------------------------------------------
// Viterbi forward. Same step semantics as the R2/R6-passing kernel (plain-C
// ring, byte stores). Changes vs R6: PF 8->16 and __launch_bounds__(64, 1).
// R3/R6 post-mortem: the ring collapsed because plain __launch_bounds__(64)
// targets 8 waves/SIMD => ~64-VGPR budget => regalloc sank the prefetch
// loads to 1-2 steps of distance => 635 cyc (LLC latency) per step. With
// min-waves=1 the allocator gets the full 512-VGPR file (grid is 32 blocks =
// 1 block/CU, so occupancy does not matter); 16-deep ring = ~1760 cyc of
// prefetch coverage > 900 cyc HBM-miss latency.
// ---------------------------------------------------------------------------
__device__ __forceinline__ void dp_stepN(int lane, const float4 la, const float4 lb,
    float (&f)[8], unsigned int laneMask, unsigned char* bpp)
{
    float lp8[8] = {la.x, la.y, la.z, la.w, lb.x, lb.y, lb.z, lb.w};
    float sh = __shfl_up(f[7], 1);
    float pm0 = (lane == 0) ? NEG : sh;
    unsigned int byt = 0u;
    #pragma unroll
    for (int j = 7; j >= 0; --j) {            // descending: f[j-1] still old
        float pm = (j == 0) ? pm0 : f[j - 1];
        byt = byt * 2u + ((f[j] < pm) ? 1u : 0u);
        f[j] = lp8[j] + fmaxf(pm, f[j]);
    }
    *bpp = (unsigned char)(byt & laneMask);
}

__device__ __forceinline__ void dp_stepD(int y, int lane, const float4 la, const float4 lb,
    float (&f)[8], unsigned int laneMask, unsigned char* bpp)
{
    float lp8[8] = {la.x, la.y, la.z, la.w, lb.x, lb.y, lb.z, lb.w};
    float sh = __shfl_up(f[7], 1);
    float edge = (y == 0) ? 0.f : NEG;
    float pm0 = (lane == 0) ? edge : sh;
    bool lanehit = (lane == (y >> 3));
    int jeq = y & 7;
    unsigned int byt = 0u;
    #pragma unroll
    for (int j = 7; j >= 0; --j) {
        float pm = (j == 0) ? pm0 : f[j - 1];
        bool ceq = lanehit && (jeq == j);
        byt = byt * 2u + (((f[j] < pm) || ceq) ? 1u : 0u);
        float vc = ceq ? NEG : f[j];
        f[j] = lp8[j] + fmaxf(pm, vc);
    }
    *bpp = (unsigned char)(byt & laneMask);
}

__global__ __launch_bounds__(64, 1) void dp_forward(const float* __restrict__ logpT,
    float* __restrict__ fsave, unsigned char* __restrict__ bits8, int y0, int C)
{
    int b = blockIdx.x, lane = threadIdx.x;
    const float* lp = logpT + (size_t)b * C * TX_ + lane * 8;
    unsigned char* bp = bits8 + ((size_t)b * TY_ + y0) * 64 + lane;
    float f[8];
    if (y0 == 0) {
        #pragma unroll
        for (int j = 0; j < 8; ++j) f[j] = NEG;
    } else {
        float4 fa = *(const float4*)(fsave + (size_t)b * TX_ + lane * 8);
        float4 fb = *(const float4*)(fsave + (size_t)b * TX_ + lane * 8 + 4);
        f[0]=fa.x; f[1]=fa.y; f[2]=fa.z; f[3]=fa.w;
        f[4]=fb.x; f[5]=fb.y; f[6]=fb.z; f[7]=fb.w;
    }
    unsigned int laneMask = (lane == 0) ? 0xFEu : 0xFFu;

    float4 bufA[PF], bufB[PF];
    #pragma unroll
    for (int s = 0; s < PF; ++s) {            // C >= 128 > PF always
        bufA[s] = *(const float4*)(lp + (size_t)s * TX_);
        bufB[s] = *(const float4*)(lp + (size_t)s * TX_ + 4);
    }
    int tD = 0;
    if (y0 < TX_) { tD = TX_ - y0; if (tD > C) tD = C; }   // multiple of PF
    int t = 0;
    for (; t < tD; t += PF) {
        #pragma unroll
        for (int s = 0; s < PF; ++s) {
            dp_stepD(y0 + t + s, lane, bufA[s], bufB[s], f, laneMask, bp + (size_t)(t + s) * 64);
            int tn = t + s + PF; if (tn >= C) tn = C - 1;
            bufA[s] = *(const float4*)(lp + (size_t)tn * TX_);
            bufB[s] = *(const float4*)(lp + (size_t)tn * TX_ + 4);
        }
    }
    for (; t < C; t += PF) {
        #pragma unroll
        for (int s = 0; s < PF; ++s) {
            dp_stepN(lane, bufA[s], bufB[s], f, laneMask, bp + (size_t)(t + s) * 64);
            int tn = t + s + PF; if (tn >= C) tn = C - 1;
            bufA[s] = *(const float4*)(lp + (size_t)tn * TX_);
            bufB[s] = *(const float4*)(lp + (size_t)tn * TX_ + 4);
        }
    }
    float4 fa = make_float4(f[0], f[1], f[2], f[3]);
    float4 fb = make_float4(f[4], f[5], f[6], f[7]);
    *(float4*)(fsave + (size_t)b * TX_ + lane * 8) = fa;
    *(float4*)(fsave + (size_t)b * TX_ + lane * 8 + 4) = fb;
}

// ---------------------------------------------------------------------------
// Backtrack. One wave per batch.
// ---------------------------------------------------------------------------
__global__ __launch_bounds__(64) void backtrack_kernel(
    const unsigned char* __restrict__ bits8, const int* __restrict__ lens,
    const float* __restrict__ x_mask, int* __restrict__ idxA, float* __restrict__ logdur)
{
    int b = blockIdx.x, lane = threadIdx.x;
    __shared__ int durS[TX_];
    for (int x = lane; x < TX_; x += 64) durS[x] = 0;
    int tx_len = lens[b];
    int ty_len = lens[B_ + b];
    int idx = tx_len - 1;
    if (idx < 0) idx = 0;
    int cnt = 0;
    const unsigned long long* bu = (const unsigned long long*)(bits8 + (size_t)b * TY_ * 64);
    for (int w = 0; w < TY_ / 64; ++w) {
        int ytop = TY_ - 1 - w * 64;
        int yl = ytop - lane;
        int Whi = idx >> 6;
        unsigned long long whi = bu[(size_t)yl * 8 + Whi];
        unsigned long long wlo = (Whi > 0) ? bu[(size_t)yl * 8 + Whi - 1] : 0ull;
        int rec = -1;
        for (int s = 0; s < 64; ++s) {
            int y = ytop - s;
            bool active = (y < ty_len);
            if (lane == s) rec = active ? idx : -1;
            if (active) cnt++;
            unsigned long long wsel = ((idx >> 6) == Whi) ? __shfl(whi, s) : __shfl(wlo, s);
            int bit = (int)((wsel >> (idx & 63)) & 1ull);
            if (active && bit) {
                if (lane == 0) durS[idx] = cnt;
                cnt = 0;
                idx -= 1;
            }
        }
        idxA[(size_t)b * TY_ + yl] = rec;
    }
    if (lane == 0) durS[idx] = cnt;
    __syncthreads();
    for (int x = lane; x < TX_; x += 64) {
        float dv = (float)durS[x];
        logdur[(size_t)b * TX_ + x] = logf(1e-8f + dv) * x_mask[(size_t)b * TX_ + x];
    }
}

// ---------------------------------------------------------------------------
__global__ __launch_bounds__(256) void attn_write(const int* __restrict__ idxA,
    const float* __restrict__ x_mask, const float* __restrict__ z_mask,
    float* __restrict__ attn_o)
{
    int b = blockIdx.z; int x = blockIdx.y;
    int yq = blockIdx.x * 256 + threadIdx.x;
    int4 iv = ((const int4*)(idxA + (size_t)b * TY_))[yq];
    float xm = x_mask[(size_t)b * TX_ + x];
    float4 zm4 = ((const float4*)(z_mask + (size_t)b * TY_))[yq];
    float4 o;
    o.x = (iv.x == x) ? xm * zm4.x : 0.f;
    o.y = (iv.y == x) ? xm * zm4.y : 0.f;
    o.z = (iv.z == x) ? xm * zm4.z : 0.f;
    o.w = (iv.w == x) ? xm * zm4.w : 0.f;
    ((float4*)(attn_o + ((size_t)(b * TX_ + x)) * TY_))[yq] = o;
}

__global__ __launch_bounds__(256) void zm_write(const int* __restrict__ idxA,
    const float* __restrict__ x_m, const float* __restrict__ x_logs,
    const float* __restrict__ x_mask, const float* __restrict__ z_mask,
    float* __restrict__ z_m_o, float* __restrict__ z_logs_o)
{
    int b = blockIdx.z; int d = blockIdx.y;
    int yq = blockIdx.x * 256 + threadIdx.x;
    int4 iv = ((const int4*)(idxA + (size_t)b * TY_))[yq];
    float4 zm4 = ((const float4*)(z_mask + (size_t)b * TY_))[yq];
    float4 om, ol;
    float* omv = (float*)&om; float* olv = (float*)&ol;
    int ivv[4] = {iv.x, iv.y, iv.z, iv.w};
    float zmv[4] = {zm4.x, zm4.y, zm4.z, zm4.w};
    #pragma unroll
    for (int c = 0; c < 4; ++c) {
        float vm = 0.f, vl = 0.f;
        int ix = ivv[c];
        if (ix >= 0) {
            float wgt = x_mask[(size_t)b * TX_ + ix] * zmv[c];
            size_t ga = ((size_t)(b * TX_ + ix)) * D_ + d;
            vm = wgt * x_m[ga];
            vl = wgt * x_logs[ga];
        }
        omv[c] = vm; olv[c] = vl;
    }
    ((float4*)(z_m_o    + ((size_t)(b * D_ + d)) * TY_))[yq] = om;
    ((float4*)(z_logs_o + ((size_t)(b * D_ + d)) * TY_))[yq] = ol;
}

// ---------------------------------------------------------------------------
extern "C" void kernel_launch(void* const* d_in, const int* in_sizes, int n_in,
                              void* d_out, int out_size, void* d_ws, size_t ws_size,
                              hipStream_t stream)
{
    const float* x_m    = (const float*)d_in[0];   // [B,TX,D]
    const float* x_logs = (const float*)d_in[1];   // [B,TX,D]
    const float* z      = (const float*)d_in[2];   // [B,D,TY]
    const float* x_mask = (const float*)d_in[3];   // [B,1,TX]
    const float* z_mask = (const float*)d_in[4];   // [B,1,TY]
    float* out = (float*)d_out;
    float* z_m_o    = out;                                   // [B,D,TY]
    float* z_logs_o = out + (size_t)B_ * D_ * TY_;           // [B,D,TY]
    float* logdur_o = out + (size_t)2 * B_ * D_ * TY_;       // [B,1,TX]
    float* attn_o   = logdur_o + (size_t)B_ * TX_;           // [B,TX,TY]

    char* p = (char*)d_ws;
    float* Cc = (float*)p;            p += (size_t)B_ * TX_ * 4;
    float* fs = (float*)p;            p += (size_t)B_ * TX_ * 4;
    unsigned char* bits8 = (unsigned char*)p; p += (size_t)B_ * TY_ * 64;
    int* idxA = (int*)p;              p += (size_t)B_ * TY_ * 4;
    int* lens = (int*)p;              p += 256;
    int* flag = (int*)p;              p += 256;
    float* logpC = (float*)p;
    size_t fixed = (size_t)(p - (char*)d_ws);
    size_t avail = (ws_size > fixed) ? (ws_size - fixed) : 0;
    int C = 128;                                   // Ty chunk for staged logp
    const int cands[5] = {2048, 1024, 512, 256, 128};
    for (int i = 0; i < 5; ++i) {
        if ((size_t)B_ * cands[i] * TX_ * 4 <= avail) { C = cands[i]; break; }
    }

    hipMemsetAsync(flag, 0, sizeof(int), stream);
    prep_kernel<<<B_ * TX_, 128, 0, stream>>>(x_m, x_logs, Cc, flag);
    lens_kernel<<<2 * B_, 256, 0, stream>>>(x_mask, z_mask, lens);
    int nc = TY_ / C;
    for (int c = 0; c < nc; ++c) {
        gemm_zero<<<dim3(TX_ / 128, C / 128, B_), 256, 0, stream>>>(
            flag, x_m, Cc, z, x_mask, z_mask, logpC, c * C, C);
        gemm_logp<<<dim3(TX_ / 64, C / 64, B_), 256, 0, stream>>>(
            flag, x_m, x_logs, Cc, z, x_mask, z_mask, logpC, c * C, C);
        dp_forward<<<B_, 64, 0, stream>>>(logpC, fs, bits8, c * C, C);
    }
    backtrack_kernel<<<B_, 64, 0, stream>>>(bits8, lens, x_mask, idxA, logdur_o);
    attn_write<<<dim3(TY_ / 4 / 256, TX_, B_), 256, 0, stream>>>(idxA, x_mask, z_mask, attn_o);
    zm_write<<<dim3(TY_ / 4 / 256, D_, B_), 256, 0, stream>>>(
        idxA, x_m, x_logs, x_mask, z_mask, z_m_o, z_logs_o);
}